// Round 17
// baseline (41.806 us; speedup 1.0000x reference)
//
#include <hip/hip_runtime.h>

#define DIM 81
#define RA  63
#define RB  32
#define ZT  32
#define XS  104   // X LDS row stride (f16)
#define OS  100   // out-staging row stride (f32)

// workspace offsets (bytes)
#define OFF_SHAA 0        // [at2][kk6][lane64][j8] f16 : 12288 B  (GEMM1 A: sha[a, i])
#define OFF_SHAT 12288    // [it3][ks4][lane64][j8] f16 : 12288 B  (GEMM2 B: sha transposed-packed)
#define OFF_SHBH 24576    // [b32][kk6][hi2][j8]   f16 :  6144 B  (shb[b, i] frag-broadcast)
#define OFF_SHBQ 30720    // [b32][it3][l32]       f32 : 12288 B  (shb[b,i]*qw[b])
#define WS_NEED  43008

// LDS layout: [0,6144) shbH | [6144,18432) shbq | [18432, +25600) xp/ob union
#define LDS_TBL   18432
#define LDS_BYTES (18432 + 25600)

typedef _Float16 half8 __attribute__((ext_vector_type(8)));
typedef _Float16 half4v __attribute__((ext_vector_type(4)));
typedef __fp16  fp16x2 __attribute__((ext_vector_type(2)));
typedef float floatx16 __attribute__((ext_vector_type(16)));

union H8U { unsigned u[4]; half8 h; };
union H2U { fp16x2 h; unsigned u; };

// ---------------- precompute packed sha/shb fragment tables (43 KB total) ----------------
__global__ __launch_bounds__(256) void precompute_fact(
    const float* __restrict__ shb, const float* __restrict__ sha,
    const float* __restrict__ qw, char* __restrict__ wsp)
{
    _Float16* shaAP = (_Float16*)(wsp + OFF_SHAA);
    _Float16* shaTP = (_Float16*)(wsp + OFF_SHAT);
    _Float16* shbHP = (_Float16*)(wsp + OFF_SHBH);
    float*    shbqP = (float*)(wsp + OFF_SHBQ);

    int idx = blockIdx.x * 256 + threadIdx.x;
    if (idx < 6144) {                       // shaAP: A-frag rows a, k = i
        int j = idx & 7, lane = (idx >> 3) & 63, g = idx >> 9;   // g = at*6+kk
        int at = g / 6, kk = g - at * 6;
        int a = at * 32 + (lane & 31);
        int i = kk * 16 + (lane >> 5) * 8 + j;
        float v = (a < RA && i < DIM) ? sha[a * DIM + i] : 0.f;
        shaAP[idx] = (_Float16)v;
    } else if (idx < 12288) {               // shaTP: B-frag cols i, k = a
        int t = idx - 6144;
        int j = t & 7, lane = (t >> 3) & 63, g = t >> 9;          // g = it*4+ks
        int it = g >> 2, ks = g & 3;
        int a = ks * 16 + (lane >> 5) * 8 + j;
        int i = it * 32 + (lane & 31);
        float v = (a < RA && i < DIM) ? sha[a * DIM + i] : 0.f;
        shaTP[t] = (_Float16)v;
    } else if (idx < 15360) {               // shbHP: per-(b,kk,hi) broadcast half8
        int t = idx - 12288;
        int j = t & 7, hi = (t >> 3) & 1, g = t >> 4;             // g = b*6+kk
        int b = g / 6, kk = g - b * 6;
        int i = kk * 16 + hi * 8 + j;
        float v = (i < DIM) ? shb[b * DIM + i] : 0.f;
        shbHP[t] = (_Float16)v;
    } else if (idx < 18432) {               // shbqP: f32 scale per (b, i)
        int t = idx - 15360;
        int l = t & 31, g = t >> 5;                               // g = b*3+it
        int b = g / 3, it = g - b * 3;
        int i = it * 32 + l;
        float v = (i < DIM) ? shb[b * DIM + i] * qw[b] : 0.f;
        shbqP[t] = v;
    }
}

// ---------------- main kernel: R16 + split-K GEMM1 (4 independent 3-deep chains) ----------------
__global__ __launch_bounds__(256, 1) void gaunt_fact(
    const float* __restrict__ x1, const float* __restrict__ x2,
    const char* __restrict__ wsp, float* __restrict__ out)
{
    const _Float16* shaAP = (const _Float16*)(wsp + OFF_SHAA);
    const _Float16* shaTP = (const _Float16*)(wsp + OFF_SHAT);

    __shared__ __align__(16) char lds[LDS_BYTES];
    const _Float16* shbH_l = (const _Float16*)lds;          // 6144 B
    const float*    shbq_l = (const float*)(lds + 6144);    // 12288 B
    _Float16* xp = (_Float16*)(lds + LDS_TBL);              // [2][ZT][XS]
    float*    ob = (float*)(lds + LDS_TBL);                 // [2][ZT][OS] (reused after xfr reads)

    const int tid = threadIdx.x;
    const int z0  = blockIdx.x * ZT;

    // stage hot tables global->LDS (shbH + shbq contiguous in wsp: 18432 B)
    for (int i = tid; i < LDS_TBL / 16; i += 256)
        ((uint4*)lds)[i] = ((const uint4*)(wsp + OFF_SHBH))[i];

    // stage X1,X2 -> f16 LDS, float4-vectorized (cols 81..95 zero; 81 = 20*4+1)
    {
        const int nv = ZT * 24;
        #pragma unroll
        for (int in = 0; in < 2; ++in) {
            const float* src = in ? x2 : x1;
            _Float16* dst = xp + in * (ZT * XS);
            for (int idx = tid; idx < nv; idx += 256) {
                int r = idx / 24, c4 = idx - r * 24;
                float4 v = make_float4(0.f, 0.f, 0.f, 0.f);
                if (c4 < 20)       v = *(const float4*)(src + (size_t)(z0 + r) * DIM + c4 * 4);
                else if (c4 == 20) v.x = src[(size_t)(z0 + r) * DIM + 80];
                half4v h;
                h[0] = (_Float16)v.x; h[1] = (_Float16)v.y;
                h[2] = (_Float16)v.z; h[3] = (_Float16)v.w;
                *(half4v*)(dst + r * XS + c4 * 4) = h;
            }
        }
    }
    __syncthreads();

    const int l = tid & 63, l31 = l & 31, hi = l >> 5;
    const int nw = tid >> 6;   // wave 0..3, owns b = nw*8 .. +8

    // X B-frags resident in VGPR (48 regs)
    half8 xfr[2][6];
    #pragma unroll
    for (int in = 0; in < 2; ++in)
        #pragma unroll
        for (int kk = 0; kk < 6; ++kk)
            xfr[in][kk] = *(const half8*)(xp + in * (ZT * XS) + l31 * XS + kk * 16 + hi * 8);
    __syncthreads();   // xp reads done; ob (aliased) writable later

    // sha A-frags (unscaled), resident (48 regs)
    half8 aAc[2][6];
    #pragma unroll
    for (int at = 0; at < 2; ++at)
        #pragma unroll
        for (int kk = 0; kk < 6; ++kk)
            aAc[at][kk] = *(const half8*)(shaAP + ((at * 6 + kk) * 64 + l) * 8);

    // GEMM2 B-frags: loop-invariant, hoisted (48 regs)
    half8 bTc[3][2][2];
    #pragma unroll
    for (int it = 0; it < 3; ++it)
        #pragma unroll
        for (int at = 0; at < 2; ++at) {
            bTc[it][at][0] = *(const half8*)(shaTP + ((it * 4 + at * 2) * 64 + l) * 8);
            bTc[it][at][1] = *(const half8*)(shaTP + ((it * 4 + at * 2 + 1) * 64 + l) * 8);
        }

    floatx16 accO[3];
    #pragma unroll
    for (int it = 0; it < 3; ++it)
        #pragma unroll
        for (int r = 0; r < 16; ++r) accO[it][r] = 0.f;

    #pragma unroll 1
    for (int bi = 0; bi < 8; ++bi) {
        const int b = nw * 8 + bi;

        unsigned f[2][8];

        // ---- GEMM1 split-K: 4 independent 3-deep chains per at
        #pragma unroll
        for (int at = 0; at < 2; ++at) {
            floatx16 g0a, g0b, g1a, g1b;
            #pragma unroll
            for (int r = 0; r < 16; ++r) { g0a[r] = 0.f; g0b[r] = 0.f; g1a[r] = 0.f; g1b[r] = 0.f; }
            __builtin_amdgcn_s_setprio(1);
            #pragma unroll
            for (int kk = 0; kk < 3; ++kk) {
                const half8 sf = *(const half8*)(shbH_l + ((b * 6 + kk) * 2 + hi) * 8);
                const half8 aS = aAc[at][kk] * sf;
                g0a = __builtin_amdgcn_mfma_f32_32x32x16_f16(aS, xfr[0][kk], g0a, 0, 0, 0);
                g1a = __builtin_amdgcn_mfma_f32_32x32x16_f16(aS, xfr[1][kk], g1a, 0, 0, 0);
            }
            #pragma unroll
            for (int kk = 3; kk < 6; ++kk) {
                const half8 sf = *(const half8*)(shbH_l + ((b * 6 + kk) * 2 + hi) * 8);
                const half8 aS = aAc[at][kk] * sf;
                g0b = __builtin_amdgcn_mfma_f32_32x32x16_f16(aS, xfr[0][kk], g0b, 0, 0, 0);
                g1b = __builtin_amdgcn_mfma_f32_32x32x16_f16(aS, xfr[1][kk], g1b, 0, 0, 0);
            }
            __builtin_amdgcn_s_setprio(0);
            // combine halves (packed adds), packed product, then cvt
            floatx16 p = (g0a + g0b) * (g1a + g1b);
            unsigned q[8];
            #pragma unroll
            for (int j = 0; j < 8; ++j) {
                H2U t;
                t.h = __builtin_amdgcn_cvt_pkrtz(p[2 * j], p[2 * j + 1]);
                q[j] = t.u;
            }
            asm volatile("v_permlane32_swap_b32 %0, %1" : "+v"(q[0]), "+v"(q[2]));
            asm volatile("v_permlane32_swap_b32 %0, %1" : "+v"(q[1]), "+v"(q[3]));
            asm volatile("v_permlane32_swap_b32 %0, %1" : "+v"(q[4]), "+v"(q[6]));
            asm volatile("v_permlane32_swap_b32 %0, %1" : "+v"(q[5]), "+v"(q[7]));
            #pragma unroll
            for (int w = 0; w < 8; ++w) f[at][w] = q[w];
        }

        // ---- GEMM2 + scaled accumulate
        const float s0 = shbq_l[(b * 3 + 0) * 32 + l31];
        const float s1 = shbq_l[(b * 3 + 1) * 32 + l31];
        const float s2 = shbq_l[(b * 3 + 2) * 32 + l31];
        #pragma unroll
        for (int it = 0; it < 3; ++it) {
            floatx16 R;
            #pragma unroll
            for (int r = 0; r < 16; ++r) R[r] = 0.f;
            __builtin_amdgcn_s_setprio(1);
            #pragma unroll
            for (int at = 0; at < 2; ++at) {
                H8U a0, a1;
                a0.u[0] = f[at][0]; a0.u[1] = f[at][1]; a0.u[2] = f[at][2]; a0.u[3] = f[at][3];
                a1.u[0] = f[at][4]; a1.u[1] = f[at][5]; a1.u[2] = f[at][6]; a1.u[3] = f[at][7];
                R = __builtin_amdgcn_mfma_f32_32x32x16_f16(a0.h, bTc[it][at][0], R, 0, 0, 0);
                R = __builtin_amdgcn_mfma_f32_32x32x16_f16(a1.h, bTc[it][at][1], R, 0, 0, 0);
            }
            __builtin_amdgcn_s_setprio(0);
            const float s = (it == 0) ? s0 : (it == 1) ? s1 : s2;
            accO[it] += R * s;   // packed v_pk_fma_f32
        }
    }

    // ---- cross-wave reduction: 4 -> 2 -> combine at store
    if (nw >= 2) {
        float* buf = ob + (nw - 2) * (ZT * OS);
        #pragma unroll
        for (int it = 0; it < 3; ++it)
            #pragma unroll
            for (int r = 0; r < 16; ++r)
                buf[((r & 3) + 8 * (r >> 2) + 4 * hi) * OS + it * 32 + l31] = accO[it][r];
    }
    __syncthreads();
    if (nw < 2) {
        float* buf = ob + nw * (ZT * OS);
        #pragma unroll
        for (int it = 0; it < 3; ++it)
            #pragma unroll
            for (int r = 0; r < 16; ++r)
                accO[it][r] += buf[((r & 3) + 8 * (r >> 2) + 4 * hi) * OS + it * 32 + l31];
    }
    __syncthreads();
    if (nw < 2) {
        float* buf = ob + nw * (ZT * OS);
        #pragma unroll
        for (int it = 0; it < 3; ++it)
            #pragma unroll
            for (int r = 0; r < 16; ++r)
                buf[((r & 3) + 8 * (r >> 2) + 4 * hi) * OS + it * 32 + l31] = accO[it][r];
    }
    __syncthreads();

    for (int idx = tid; idx < ZT * DIM; idx += 256) {
        int zz = idx / DIM, ii = idx - zz * DIM;
        out[(size_t)z0 * DIM + idx] = ob[zz * OS + ii] + ob[ZT * OS + zz * OS + ii];
    }
}

// ---------------- fp32 fallback (round-1 kernel; needs no workspace) ----------------
__device__ __forceinline__ float wave_sum64(float v) {
    v += __int_as_float(__builtin_amdgcn_update_dpp(0, __float_as_int(v), 0x111, 0xf, 0xf, true));
    v += __int_as_float(__builtin_amdgcn_update_dpp(0, __float_as_int(v), 0x112, 0xf, 0xf, true));
    v += __int_as_float(__builtin_amdgcn_update_dpp(0, __float_as_int(v), 0x114, 0xf, 0xf, true));
    v += __int_as_float(__builtin_amdgcn_update_dpp(0, __float_as_int(v), 0x118, 0xf, 0xf, true));
    v += __int_as_float(__builtin_amdgcn_update_dpp(0, __float_as_int(v), 0x142, 0xf, 0xf, true));
    v += __int_as_float(__builtin_amdgcn_update_dpp(0, __float_as_int(v), 0x143, 0xf, 0xf, true));
    return v;
}

__global__ __launch_bounds__(256) void gaunt_s2grid_kernel(
    const float* __restrict__ x1, const float* __restrict__ x2,
    const float* __restrict__ shb, const float* __restrict__ sha,
    const float* __restrict__ qw, float* __restrict__ out)
{
    __shared__ float sha_s[64 * DIM];
    __shared__ float part[4 * DIM];
    const int tid = threadIdx.x;
    const int z = blockIdx.x;
    for (int idx = tid; idx < 64 * DIM; idx += 256)
        sha_s[idx] = (idx < RA * DIM) ? sha[idx] : 0.0f;
    __syncthreads();
    const int lane = tid & 63;
    const int w = __builtin_amdgcn_readfirstlane(tid >> 6);
    const int b0 = w * 8;
    const float* xz1 = x1 + (size_t)z * DIM;
    const float* xz2 = x2 + (size_t)z * DIM;
    const float* sha_row = sha_s + lane * DIM;
    float g1[8], g2[8];
    #pragma unroll
    for (int bb = 0; bb < 8; ++bb) { g1[bb] = 0.0f; g2[bb] = 0.0f; }
    #pragma unroll 4
    for (int i = 0; i < DIM; ++i) {
        const float sv = sha_row[i];
        const float t1 = xz1[i] * sv, t2 = xz2[i] * sv;
        #pragma unroll
        for (int bb = 0; bb < 8; ++bb) {
            const float h = shb[(b0 + bb) * DIM + i];
            g1[bb] = fmaf(h, t1, g1[bb]);
            g2[bb] = fmaf(h, t2, g2[bb]);
        }
    }
    float q[8];
    #pragma unroll
    for (int bb = 0; bb < 8; ++bb) q[bb] = g1[bb] * g2[bb] * qw[b0 + bb];
    #pragma unroll 4
    for (int i = 0; i < DIM; ++i) {
        float t = 0.0f;
        #pragma unroll
        for (int bb = 0; bb < 8; ++bb) t = fmaf(q[bb], shb[(b0 + bb) * DIM + i], t);
        float v = wave_sum64(t * sha_row[i]);
        if (lane == 63) part[w * DIM + i] = v;
    }
    __syncthreads();
    for (int i = tid; i < DIM; i += 256)
        out[(size_t)z * DIM + i] = part[i] + part[DIM + i] + part[2 * DIM + i] + part[3 * DIM + i];
}

extern "C" void kernel_launch(void* const* d_in, const int* in_sizes, int n_in,
                              void* d_out, int out_size, void* d_ws, size_t ws_size,
                              hipStream_t stream) {
    const float* x1  = (const float*)d_in[0];
    const float* x2  = (const float*)d_in[1];
    const float* shb = (const float*)d_in[2];
    const float* sha = (const float*)d_in[3];
    const float* qw  = (const float*)d_in[4];
    float* out = (float*)d_out;

    const int Z = in_sizes[0] / DIM;   // 16384

    if (ws_size >= WS_NEED && (Z % ZT) == 0) {
        char* wsp = (char*)d_ws;
        precompute_fact<<<72, 256, 0, stream>>>(shb, sha, qw, wsp);
        gaunt_fact<<<Z / ZT, 256, 0, stream>>>(x1, x2, wsp, out);
    } else {
        gaunt_s2grid_kernel<<<Z, 256, 0, stream>>>(x1, x2, shb, sha, qw, out);
    }
}

// Round 18
// 35.542 us; speedup vs baseline: 1.1763x; 1.1763x over previous
//
#include <hip/hip_runtime.h>

#define DIM 81
#define RA  63
#define RB  32
#define ZT  64
#define XS  104   // X LDS row stride (f16)
#define OS  100   // out-staging row stride (f32)

// workspace offsets (bytes)
#define OFF_SHAA 0        // [at2][kk6][lane64][j8] f16 : 12288 B  (GEMM1 A: sha[a, i])
#define OFF_SHAT 12288    // [it3][ks4][lane64][j8] f16 : 12288 B  (GEMM2 B: sha transposed-packed)
#define OFF_SHBH 24576    // [b32][kk6][hi2][j8]   f16 :  6144 B  (shb[b, i] frag-broadcast)
#define OFF_SHBQ 30720    // [b32][it3][l32]       f32 : 12288 B  (shb[b,i]*qw[b])
#define WS_NEED  43008

// LDS: [0,12288) shaT | [12288,18432) shbH | [18432,30720) shbq | [30720, +51200) xp/ob union
#define LDS_TBL   30720
#define LDS_BYTES (30720 + 51200)

typedef _Float16 half8 __attribute__((ext_vector_type(8)));
typedef _Float16 half4v __attribute__((ext_vector_type(4)));
typedef __fp16  fp16x2 __attribute__((ext_vector_type(2)));
typedef float floatx16 __attribute__((ext_vector_type(16)));

union H8U { unsigned u[4]; half8 h; };
union H2U { fp16x2 h; unsigned u; };

// ---------------- precompute packed sha/shb fragment tables (43 KB total) ----------------
__global__ __launch_bounds__(256) void precompute_fact(
    const float* __restrict__ shb, const float* __restrict__ sha,
    const float* __restrict__ qw, char* __restrict__ wsp)
{
    _Float16* shaAP = (_Float16*)(wsp + OFF_SHAA);
    _Float16* shaTP = (_Float16*)(wsp + OFF_SHAT);
    _Float16* shbHP = (_Float16*)(wsp + OFF_SHBH);
    float*    shbqP = (float*)(wsp + OFF_SHBQ);

    int idx = blockIdx.x * 256 + threadIdx.x;
    if (idx < 6144) {                       // shaAP: A-frag rows a, k = i
        int j = idx & 7, lane = (idx >> 3) & 63, g = idx >> 9;   // g = at*6+kk
        int at = g / 6, kk = g - at * 6;
        int a = at * 32 + (lane & 31);
        int i = kk * 16 + (lane >> 5) * 8 + j;
        float v = (a < RA && i < DIM) ? sha[a * DIM + i] : 0.f;
        shaAP[idx] = (_Float16)v;
    } else if (idx < 12288) {               // shaTP: B-frag cols i, k = a
        int t = idx - 6144;
        int j = t & 7, lane = (t >> 3) & 63, g = t >> 9;          // g = it*4+ks
        int it = g >> 2, ks = g & 3;
        int a = ks * 16 + (lane >> 5) * 8 + j;
        int i = it * 32 + (lane & 31);
        float v = (a < RA && i < DIM) ? sha[a * DIM + i] : 0.f;
        shaTP[t] = (_Float16)v;
    } else if (idx < 15360) {               // shbHP: per-(b,kk,hi) broadcast half8
        int t = idx - 12288;
        int j = t & 7, hi = (t >> 3) & 1, g = t >> 4;             // g = b*6+kk
        int b = g / 6, kk = g - b * 6;
        int i = kk * 16 + hi * 8 + j;
        float v = (i < DIM) ? shb[b * DIM + i] : 0.f;
        shbHP[t] = (_Float16)v;
    } else if (idx < 18432) {               // shbqP: f32 scale per (b, i)
        int t = idx - 15360;
        int l = t & 31, g = t >> 5;                               // g = b*3+it
        int b = g / 3, it = g - b * 3;
        int i = it * 32 + l;
        float v = (i < DIM) ? shb[b * DIM + i] * qw[b] : 0.f;
        shbqP[t] = v;
    }
}

// ---------------- main kernel: ZT=64, grid=256 (1 block/CU), dual z-tile ILP ----------------
__global__ __launch_bounds__(256, 1) void gaunt_fact(
    const float* __restrict__ x1, const float* __restrict__ x2,
    const char* __restrict__ wsp, float* __restrict__ out)
{
    const _Float16* shaAP = (const _Float16*)(wsp + OFF_SHAA);

    __shared__ __align__(16) char lds[LDS_BYTES];
    const _Float16* shaT_l = (const _Float16*)lds;            // 12288 B
    const _Float16* shbH_l = (const _Float16*)(lds + 12288);  // 6144 B
    const float*    shbq_l = (const float*)(lds + 18432);     // 12288 B
    _Float16* xp = (_Float16*)(lds + LDS_TBL);                // [2][ZT][XS] = 26624 B
    float*    ob = (float*)(lds + LDS_TBL);                   // [2][ZT][OS] = 51200 B (union)

    const int tid = threadIdx.x;
    const int z0  = blockIdx.x * ZT;

    // stage tables global->LDS (shaT + shbH + shbq contiguous in wsp: 30720 B)
    for (int i = tid; i < LDS_TBL / 16; i += 256)
        ((uint4*)lds)[i] = ((const uint4*)(wsp + OFF_SHAT))[i];

    // stage X1,X2 -> f16 LDS, float4-vectorized (cols 81..95 zero; 81 = 20*4+1)
    {
        const int nv = ZT * 24;
        #pragma unroll
        for (int in = 0; in < 2; ++in) {
            const float* src = in ? x2 : x1;
            _Float16* dst = xp + in * (ZT * XS);
            for (int idx = tid; idx < nv; idx += 256) {
                int r = idx / 24, c4 = idx - r * 24;
                float4 v = make_float4(0.f, 0.f, 0.f, 0.f);
                if (c4 < 20)       v = *(const float4*)(src + (size_t)(z0 + r) * DIM + c4 * 4);
                else if (c4 == 20) v.x = src[(size_t)(z0 + r) * DIM + 80];
                half4v h;
                h[0] = (_Float16)v.x; h[1] = (_Float16)v.y;
                h[2] = (_Float16)v.z; h[3] = (_Float16)v.w;
                *(half4v*)(dst + r * XS + c4 * 4) = h;
            }
        }
    }
    __syncthreads();

    const int l = tid & 63, l31 = l & 31, hi = l >> 5;
    const int nw = tid >> 6;   // wave 0..3, owns b = nw*8 .. +8

    // X B-frags resident: [in][ztile][kk] (96 regs)
    half8 xfr[2][2][6];
    #pragma unroll
    for (int in = 0; in < 2; ++in)
        #pragma unroll
        for (int zt = 0; zt < 2; ++zt)
            #pragma unroll
            for (int kk = 0; kk < 6; ++kk)
                xfr[in][zt][kk] = *(const half8*)(xp + in * (ZT * XS) + (zt * 32 + l31) * XS + kk * 16 + hi * 8);
    __syncthreads();   // xp reads done; ob (aliased) writable later

    // sha A-frags (unscaled), resident (48 regs)
    half8 aAc[2][6];
    #pragma unroll
    for (int at = 0; at < 2; ++at)
        #pragma unroll
        for (int kk = 0; kk < 6; ++kk)
            aAc[at][kk] = *(const half8*)(shaAP + ((at * 6 + kk) * 64 + l) * 8);

    floatx16 accO[2][3];   // [ztile][it] — 96 regs (AGPR-eligible)
    #pragma unroll
    for (int zt = 0; zt < 2; ++zt)
        #pragma unroll
        for (int it = 0; it < 3; ++it)
            #pragma unroll
            for (int r = 0; r < 16; ++r) accO[zt][it][r] = 0.f;

    #pragma unroll 1
    for (int bi = 0; bi < 8; ++bi) {
        const int b = nw * 8 + bi;

        unsigned f0[2][8], f1[2][8];   // [at][word] for ztile 0 / 1

        // ---- GEMM1: 4 independent 6-deep chains per at (in x ztile); aS amortized x4
        #pragma unroll
        for (int at = 0; at < 2; ++at) {
            floatx16 g00, g01, g10, g11;   // [in][zt]
            #pragma unroll
            for (int r = 0; r < 16; ++r) { g00[r] = 0.f; g01[r] = 0.f; g10[r] = 0.f; g11[r] = 0.f; }
            __builtin_amdgcn_s_setprio(1);
            #pragma unroll
            for (int kk = 0; kk < 6; ++kk) {
                const half8 sf = *(const half8*)(shbH_l + ((b * 6 + kk) * 2 + hi) * 8);
                const half8 aS = aAc[at][kk] * sf;
                g00 = __builtin_amdgcn_mfma_f32_32x32x16_f16(aS, xfr[0][0][kk], g00, 0, 0, 0);
                g10 = __builtin_amdgcn_mfma_f32_32x32x16_f16(aS, xfr[1][0][kk], g10, 0, 0, 0);
                g01 = __builtin_amdgcn_mfma_f32_32x32x16_f16(aS, xfr[0][1][kk], g01, 0, 0, 0);
                g11 = __builtin_amdgcn_mfma_f32_32x32x16_f16(aS, xfr[1][1][kk], g11, 0, 0, 0);
            }
            __builtin_amdgcn_s_setprio(0);
            floatx16 p0 = g00 * g10;   // ztile 0: in0*in1
            floatx16 p1 = g01 * g11;   // ztile 1
            unsigned q0[8], q1[8];
            #pragma unroll
            for (int j = 0; j < 8; ++j) {
                H2U t0, t1;
                t0.h = __builtin_amdgcn_cvt_pkrtz(p0[2 * j], p0[2 * j + 1]);
                t1.h = __builtin_amdgcn_cvt_pkrtz(p1[2 * j], p1[2 * j + 1]);
                q0[j] = t0.u; q1[j] = t1.u;
            }
            asm volatile("v_permlane32_swap_b32 %0, %1" : "+v"(q0[0]), "+v"(q0[2]));
            asm volatile("v_permlane32_swap_b32 %0, %1" : "+v"(q0[1]), "+v"(q0[3]));
            asm volatile("v_permlane32_swap_b32 %0, %1" : "+v"(q0[4]), "+v"(q0[6]));
            asm volatile("v_permlane32_swap_b32 %0, %1" : "+v"(q0[5]), "+v"(q0[7]));
            asm volatile("v_permlane32_swap_b32 %0, %1" : "+v"(q1[0]), "+v"(q1[2]));
            asm volatile("v_permlane32_swap_b32 %0, %1" : "+v"(q1[1]), "+v"(q1[3]));
            asm volatile("v_permlane32_swap_b32 %0, %1" : "+v"(q1[4]), "+v"(q1[6]));
            asm volatile("v_permlane32_swap_b32 %0, %1" : "+v"(q1[5]), "+v"(q1[7]));
            #pragma unroll
            for (int w = 0; w < 8; ++w) { f0[at][w] = q0[w]; f1[at][w] = q1[w]; }
        }

        // ---- GEMM2: 6 independent R chains (ztile x it); bT from LDS (shared)
        const float s0 = shbq_l[(b * 3 + 0) * 32 + l31];
        const float s1 = shbq_l[(b * 3 + 1) * 32 + l31];
        const float s2 = shbq_l[(b * 3 + 2) * 32 + l31];
        #pragma unroll
        for (int it = 0; it < 3; ++it) {
            floatx16 R0, R1;
            #pragma unroll
            for (int r = 0; r < 16; ++r) { R0[r] = 0.f; R1[r] = 0.f; }
            __builtin_amdgcn_s_setprio(1);
            #pragma unroll
            for (int at = 0; at < 2; ++at) {
                const half8 bT0 = *(const half8*)(shaT_l + ((it * 4 + at * 2) * 64 + l) * 8);
                const half8 bT1 = *(const half8*)(shaT_l + ((it * 4 + at * 2 + 1) * 64 + l) * 8);
                H8U a00, a01, a10, a11;
                a00.u[0] = f0[at][0]; a00.u[1] = f0[at][1]; a00.u[2] = f0[at][2]; a00.u[3] = f0[at][3];
                a01.u[0] = f0[at][4]; a01.u[1] = f0[at][5]; a01.u[2] = f0[at][6]; a01.u[3] = f0[at][7];
                a10.u[0] = f1[at][0]; a10.u[1] = f1[at][1]; a10.u[2] = f1[at][2]; a10.u[3] = f1[at][3];
                a11.u[0] = f1[at][4]; a11.u[1] = f1[at][5]; a11.u[2] = f1[at][6]; a11.u[3] = f1[at][7];
                R0 = __builtin_amdgcn_mfma_f32_32x32x16_f16(a00.h, bT0, R0, 0, 0, 0);
                R0 = __builtin_amdgcn_mfma_f32_32x32x16_f16(a01.h, bT1, R0, 0, 0, 0);
                R1 = __builtin_amdgcn_mfma_f32_32x32x16_f16(a10.h, bT0, R1, 0, 0, 0);
                R1 = __builtin_amdgcn_mfma_f32_32x32x16_f16(a11.h, bT1, R1, 0, 0, 0);
            }
            __builtin_amdgcn_s_setprio(0);
            const float s = (it == 0) ? s0 : (it == 1) ? s1 : s2;
            accO[0][it] += R0 * s;
            accO[1][it] += R1 * s;
        }
    }

    // ---- cross-wave reduction: 4 -> 2 -> combine at store (rows span 64 z)
    if (nw >= 2) {
        float* buf = ob + (nw - 2) * (ZT * OS);
        #pragma unroll
        for (int zt = 0; zt < 2; ++zt)
            #pragma unroll
            for (int it = 0; it < 3; ++it)
                #pragma unroll
                for (int r = 0; r < 16; ++r)
                    buf[(zt * 32 + (r & 3) + 8 * (r >> 2) + 4 * hi) * OS + it * 32 + l31] = accO[zt][it][r];
    }
    __syncthreads();
    if (nw < 2) {
        float* buf = ob + nw * (ZT * OS);
        #pragma unroll
        for (int zt = 0; zt < 2; ++zt)
            #pragma unroll
            for (int it = 0; it < 3; ++it)
                #pragma unroll
                for (int r = 0; r < 16; ++r)
                    accO[zt][it][r] += buf[(zt * 32 + (r & 3) + 8 * (r >> 2) + 4 * hi) * OS + it * 32 + l31];
    }
    __syncthreads();
    if (nw < 2) {
        float* buf = ob + nw * (ZT * OS);
        #pragma unroll
        for (int zt = 0; zt < 2; ++zt)
            #pragma unroll
            for (int it = 0; it < 3; ++it)
                #pragma unroll
                for (int r = 0; r < 16; ++r)
                    buf[(zt * 32 + (r & 3) + 8 * (r >> 2) + 4 * hi) * OS + it * 32 + l31] = accO[zt][it][r];
    }
    __syncthreads();

    for (int idx = tid; idx < ZT * DIM; idx += 256) {
        int zz = idx / DIM, ii = idx - zz * DIM;
        out[(size_t)z0 * DIM + idx] = ob[zz * OS + ii] + ob[ZT * OS + zz * OS + ii];
    }
}

// ---------------- fp32 fallback (round-1 kernel; needs no workspace) ----------------
__device__ __forceinline__ float wave_sum64(float v) {
    v += __int_as_float(__builtin_amdgcn_update_dpp(0, __float_as_int(v), 0x111, 0xf, 0xf, true));
    v += __int_as_float(__builtin_amdgcn_update_dpp(0, __float_as_int(v), 0x112, 0xf, 0xf, true));
    v += __int_as_float(__builtin_amdgcn_update_dpp(0, __float_as_int(v), 0x114, 0xf, 0xf, true));
    v += __int_as_float(__builtin_amdgcn_update_dpp(0, __float_as_int(v), 0x118, 0xf, 0xf, true));
    v += __int_as_float(__builtin_amdgcn_update_dpp(0, __float_as_int(v), 0x142, 0xf, 0xf, true));
    v += __int_as_float(__builtin_amdgcn_update_dpp(0, __float_as_int(v), 0x143, 0xf, 0xf, true));
    return v;
}

__global__ __launch_bounds__(256) void gaunt_s2grid_kernel(
    const float* __restrict__ x1, const float* __restrict__ x2,
    const float* __restrict__ shb, const float* __restrict__ sha,
    const float* __restrict__ qw, float* __restrict__ out)
{
    __shared__ float sha_s[64 * DIM];
    __shared__ float part[4 * DIM];
    const int tid = threadIdx.x;
    const int z = blockIdx.x;
    for (int idx = tid; idx < 64 * DIM; idx += 256)
        sha_s[idx] = (idx < RA * DIM) ? sha[idx] : 0.0f;
    __syncthreads();
    const int lane = tid & 63;
    const int w = __builtin_amdgcn_readfirstlane(tid >> 6);
    const int b0 = w * 8;
    const float* xz1 = x1 + (size_t)z * DIM;
    const float* xz2 = x2 + (size_t)z * DIM;
    const float* sha_row = sha_s + lane * DIM;
    float g1[8], g2[8];
    #pragma unroll
    for (int bb = 0; bb < 8; ++bb) { g1[bb] = 0.0f; g2[bb] = 0.0f; }
    #pragma unroll 4
    for (int i = 0; i < DIM; ++i) {
        const float sv = sha_row[i];
        const float t1 = xz1[i] * sv, t2 = xz2[i] * sv;
        #pragma unroll
        for (int bb = 0; bb < 8; ++bb) {
            const float h = shb[(b0 + bb) * DIM + i];
            g1[bb] = fmaf(h, t1, g1[bb]);
            g2[bb] = fmaf(h, t2, g2[bb]);
        }
    }
    float q[8];
    #pragma unroll
    for (int bb = 0; bb < 8; ++bb) q[bb] = g1[bb] * g2[bb] * qw[b0 + bb];
    #pragma unroll 4
    for (int i = 0; i < DIM; ++i) {
        float t = 0.0f;
        #pragma unroll
        for (int bb = 0; bb < 8; ++bb) t = fmaf(q[bb], shb[(b0 + bb) * DIM + i], t);
        float v = wave_sum64(t * sha_row[i]);
        if (lane == 63) part[w * DIM + i] = v;
    }
    __syncthreads();
    for (int i = tid; i < DIM; i += 256)
        out[(size_t)z * DIM + i] = part[i] + part[DIM + i] + part[2 * DIM + i] + part[3 * DIM + i];
}

extern "C" void kernel_launch(void* const* d_in, const int* in_sizes, int n_in,
                              void* d_out, int out_size, void* d_ws, size_t ws_size,
                              hipStream_t stream) {
    const float* x1  = (const float*)d_in[0];
    const float* x2  = (const float*)d_in[1];
    const float* shb = (const float*)d_in[2];
    const float* sha = (const float*)d_in[3];
    const float* qw  = (const float*)d_in[4];
    float* out = (float*)d_out;

    const int Z = in_sizes[0] / DIM;   // 16384

    if (ws_size >= WS_NEED && (Z % ZT) == 0) {
        char* wsp = (char*)d_ws;
        precompute_fact<<<72, 256, 0, stream>>>(shb, sha, qw, wsp);
        gaunt_fact<<<Z / ZT, 256, 0, stream>>>(x1, x2, wsp, out);
    } else {
        gaunt_s2grid_kernel<<<Z, 256, 0, stream>>>(x1, x2, shb, sha, qw, out);
    }
}